// Round 6
// baseline (162.519 us; speedup 1.0000x reference)
//
#include <hip/hip_runtime.h>
#include <hip/hip_bf16.h>
#include <stdint.h>

typedef __bf16 bf16;
typedef __bf16 bf16x4 __attribute__((ext_vector_type(4)));
typedef __bf16 bf16x8 __attribute__((ext_vector_type(8)));
typedef float  f32x4  __attribute__((ext_vector_type(4)));

#define DEV __device__ __forceinline__

// ---- constants for this problem ----
#define BB 2
#define HH 16
#define SS 1024
#define DD 1024
#define HD 64
#define LC 1024
#define TT 2048   // LC + SS
#define OFFS 1024 // TT - SS (causal offset)

DEV f32x4 mfma16(bf16x8 a, bf16x8 b, f32x4 c) {
    return __builtin_amdgcn_mfma_f32_16x16x32_bf16(a, b, c, 0, 0, 0);
}

// async global->LDS, 16B per lane. LDS dest must be wave-uniform base + lane*16.
DEV void async_load16(const bf16* g, bf16* lds) {
    auto gp = reinterpret_cast<const __attribute__((address_space(1))) void*>(
        reinterpret_cast<uintptr_t>(g));
    auto lp = reinterpret_cast<__attribute__((address_space(3))) void*>(
        reinterpret_cast<uintptr_t>(lds));
    __builtin_amdgcn_global_load_lds(gp, lp, 16, 0, 0);
}

// ---------------------------------------------------------------------------
// One merged conversion kernel:
//   blocks [0,2048)        : x fp32 -> xb bf16
//   blocks [2048,6144)     : Wq/Wk/Wv/Wo fp32 -> bf16 (wq/wk/wv contiguous!)
//   blocks [6144,8192)     : cache_k -> Kfull rows [0,LC)
//   blocks [8192,8704)     : cache_v -> VT cols [0,LC) (64x64 transpose)
// ---------------------------------------------------------------------------
__global__ __launch_bounds__(256) void cvt_all(
    const float* __restrict__ x,  bf16* __restrict__ xb,
    const float* __restrict__ w0, const float* __restrict__ w1,
    const float* __restrict__ w2, const float* __restrict__ w3,
    bf16* __restrict__ d0, bf16* __restrict__ d1,
    bf16* __restrict__ d2, bf16* __restrict__ d3,
    const float* __restrict__ ck, bf16* __restrict__ Kf,
    const float* __restrict__ cv, bf16* __restrict__ Vt) {
    __shared__ float tile[64][65];
    const int bid = blockIdx.x;
    const int tid = threadIdx.x;
    if (bid < 8192) {
        const float* s;
        bf16* d;
        int i;
        if (bid < 2048) {                       // x
            s = x; d = xb; i = bid * 256 + tid;
        } else if (bid < 6144) {                // weights
            int which = (bid - 2048) >> 10;
            s = which == 0 ? w0 : which == 1 ? w1 : which == 2 ? w2 : w3;
            d = which == 0 ? d0 : which == 1 ? d1 : which == 2 ? d2 : d3;
            i = ((bid - 2048) & 1023) * 256 + tid;
        } else {                                // cache_k (with row re-base)
            int ii = (bid - 6144) * 256 + tid;
            int bh  = ii >> 14;                 // 16384 float4 per bh
            int rem = ii & 16383;
            float4 v = ((const float4*)ck)[ii];
            bf16x4 o;
            o[0] = (bf16)v.x; o[1] = (bf16)v.y; o[2] = (bf16)v.z; o[3] = (bf16)v.w;
            ((bf16x4*)(Kf + (size_t)bh * TT * HD))[rem] = o;
            return;
        }
        float4 v = ((const float4*)s)[i];
        bf16x4 o;
        o[0] = (bf16)v.x; o[1] = (bf16)v.y; o[2] = (bf16)v.z; o[3] = (bf16)v.w;
        ((bf16x4*)d)[i] = o;
    } else {                                    // cache_v transpose
        int rem = bid - 8192;
        int bh = rem >> 4;
        int t0 = (rem & 15) * 64;
        int c4 = (tid & 15) * 4;
        int rr = tid >> 4;
        const float* src = cv + ((size_t)bh * LC + t0) * HD;
#pragma unroll
        for (int p = 0; p < 4; ++p) {
            int t = rr + p * 16;
            float4 v = *(const float4*)(src + (size_t)t * HD + c4);
            tile[c4 + 0][t] = v.x; tile[c4 + 1][t] = v.y;
            tile[c4 + 2][t] = v.z; tile[c4 + 3][t] = v.w;
        }
        __syncthreads();
        bf16* dst = Vt + (size_t)bh * HD * TT + t0;
#pragma unroll
        for (int p = 0; p < 4; ++p) {
            int d = rr + p * 16;
            int tc = (tid & 15) * 4;
            bf16x4 o;
            o[0] = (bf16)tile[d][tc + 0]; o[1] = (bf16)tile[d][tc + 1];
            o[2] = (bf16)tile[d][tc + 2]; o[3] = (bf16)tile[d][tc + 3];
            *(bf16x4*)(dst + (size_t)d * TT + tc) = o;
        }
    }
}

// ---------------------------------------------------------------------------
// NT GEMM v2: Y[m,n] = sum_k A[m,k] * W[n,k] + bias[n].  K = 1024.
//   BM=64, BN=128, BK=64; 4 waves, wave tile 64x32 (n-split).
//   Double-buffered LDS, one barrier per K-step, global_load_lds(16B)
//   prefetch of tile k+1 under compute of tile k, XOR chunk swizzle.
// ---------------------------------------------------------------------------
__global__ __launch_bounds__(256) void gemm_nt(
    const bf16* __restrict__ A, const bf16* __restrict__ W,
    const float* __restrict__ bq, const float* __restrict__ bk,
    const float* __restrict__ bv, const float* __restrict__ bo,
    bf16* __restrict__ Qb, bf16* __restrict__ Kf, bf16* __restrict__ Vt,
    float* __restrict__ Out, int is_oproj) {
    const int tid  = threadIdx.x;
    const int wv   = tid >> 6;
    const int lane = tid & 63;
    const int l16  = lane & 15;
    const int quad = lane >> 4;
    const int m0 = blockIdx.y * 64;
    const int n0 = blockIdx.x * 128;
    const int mode = is_oproj ? 3 : (n0 >> 10);
    const float* bias = (mode == 0) ? bq : (mode == 1) ? bk : (mode == 2) ? bv : bo;

    __shared__ __align__(16) bf16 As[2][64 * 64];
    __shared__ __align__(16) bf16 Bs[2][128 * 64];

    f32x4 acc[4][2];
#pragma unroll
    for (int i = 0; i < 4; ++i)
#pragma unroll
        for (int j = 0; j < 2; ++j) {
            f32x4 z = {0.f, 0.f, 0.f, 0.f};
            acc[i][j] = z;
        }

    // stage K-step k0 into buffer b (A: 512 chunks, B: 1024 chunks, XOR swizzle)
    auto stage = [&](int k0, int b) {
#pragma unroll
        for (int k = 0; k < 2; ++k) {
            int seg = k * 256 + tid;
            int row = seg >> 3;
            int c   = (seg & 7) ^ (row & 7);
            async_load16(A + (size_t)(m0 + row) * 1024 + k0 + c * 8, &As[b][seg * 8]);
        }
#pragma unroll
        for (int k = 0; k < 4; ++k) {
            int seg = k * 256 + tid;
            int row = seg >> 3;
            int c   = (seg & 7) ^ (row & 7);
            async_load16(W + (size_t)(n0 + row) * 1024 + k0 + c * 8, &Bs[b][seg * 8]);
        }
    };

    stage(0, 0);

    for (int it = 0; it < 16; ++it) {
        __syncthreads();               // buf it&1 staged; prior buf free
        const bf16* Ab = &As[it & 1][0];
        const bf16* Bb = &Bs[it & 1][0];
        if (it + 1 < 16) stage((it + 1) * 64, (it + 1) & 1);

#pragma unroll
        for (int kk = 0; kk < 2; ++kk) {
            bf16x8 af[4], bfr[2];
#pragma unroll
            for (int i = 0; i < 4; ++i) {
                int row = i * 16 + l16;
                int slot = (kk * 4 + quad) ^ (row & 7);
                af[i] = *(const bf16x8*)(Ab + (row * 8 + slot) * 8);
            }
#pragma unroll
            for (int j = 0; j < 2; ++j) {
                int row = wv * 32 + j * 16 + l16;
                int slot = (kk * 4 + quad) ^ (row & 7);
                bfr[j] = *(const bf16x8*)(Bb + (row * 8 + slot) * 8);
            }
#pragma unroll
            for (int i = 0; i < 4; ++i)
#pragma unroll
                for (int j = 0; j < 2; ++j)
                    acc[i][j] = mfma16(af[i], bfr[j], acc[i][j]);
        }
    }

    // epilogue: C layout col = l16 (n), row = quad*4 + r (m)
#pragma unroll
    for (int i = 0; i < 4; ++i) {
#pragma unroll
        for (int j = 0; j < 2; ++j) {
            int n = n0 + wv * 32 + j * 16 + l16;
            float bval = bias[n & 1023];
#pragma unroll
            for (int r = 0; r < 4; ++r) {
                int m = m0 + i * 16 + quad * 4 + r;
                float v = acc[i][j][r] + bval;
                if (mode == 3) {
                    Out[(size_t)m * 1024 + n] = v;
                } else {
                    int b = m >> 10, s = m & 1023;
                    int h = (n & 1023) >> 6, d = n & 63;
                    int bh = b * HH + h;
                    if (mode == 0)
                        Qb[((size_t)bh * SS + s) * HD + d] = (bf16)v;
                    else if (mode == 1)
                        Kf[((size_t)bh * TT + LC + s) * HD + d] = (bf16)v;
                    else
                        Vt[((size_t)bh * HD + d) * TT + LC + s] = (bf16)v;
                }
            }
        }
    }
}

// ---------------------------------------------------------------------------
// Flash attention v5: S^T formulation, fixed-max softmax, 2x2 (q x key) wave
// decomposition (R4) with the PV k-permutation FIXED (R4 bug): P^T holds keys
// in permuted order {kbase+quad*4+j, kbase+16+quad*4+j}; the V A-operand must
// use the SAME permutation -> chunk kh*4+q1 / kh*4+2+q1 at offset h4
// (q1=quad>>1, h4=(quad&1)*4), exactly as in the verified R2/R3 kernel.
// ---------------------------------------------------------------------------
__global__ __launch_bounds__(256) void attn(const bf16* __restrict__ Qb,
                                            const bf16* __restrict__ Kf,
                                            const bf16* __restrict__ Vt,
                                            bf16* __restrict__ Ob) {
    const int i = blockIdx.x;
    const int bh = i & 31;
    const int qblk = (i < 256) ? (15 - (i >> 5)) : ((i >> 5) - 8);
    const int tid  = threadIdx.x;
    const int wv   = tid >> 6;
    const int qh   = wv & 1;
    const int kh   = wv >> 1;
    const int lane = tid & 63;
    const int l16  = lane & 15;
    const int quad = lane >> 4;
    const int qb   = qblk * 64;            // block q base
    const int qw   = qb + qh * 32;         // wave q base (32 rows)

    const bf16* Qp = Qb + ((size_t)bh * SS + qw) * HD;
    const bf16* Kp = Kf + (size_t)bh * TT * HD;
    const bf16* Vp = Vt + (size_t)bh * HD * TT;

    __shared__ __align__(16) bf16 Ks[2][64 * 64];
    __shared__ __align__(16) bf16 Vs[2][64 * 64];

    // Q as B-operand: qf[qs][dc] = B[k=d=dc*32+quad*8+j][n=q=qs*16+l16]
    bf16x8 qf[2][2];
#pragma unroll
    for (int qs = 0; qs < 2; ++qs)
#pragma unroll
        for (int dc = 0; dc < 2; ++dc)
            qf[qs][dc] = *(const bf16x8*)(Qp + (qs * 16 + l16) * HD + dc * 32 + quad * 8);

    float lsum[2] = {0.f, 0.f};
    f32x4 o[4][2];
#pragma unroll
    for (int dt = 0; dt < 4; ++dt)
#pragma unroll
        for (int qs = 0; qs < 2; ++qs) {
            f32x4 z = {0.f, 0.f, 0.f, 0.f};
            o[dt][qs] = z;
        }

    const int niters = qblk + 17;   // (qb + 64 + OFFS) / 64

    // stage tile (keys [tile*64, tile*64+64)) into buffer b; XOR column swizzle
    auto stage = [&](int tile, int b) {
        const int t0 = tile * 64;
#pragma unroll
        for (int j = 0; j < 2; ++j) {
            int seg = (j * 4 + wv) * 64 + lane;   // 0..511
            int row = seg >> 3;                    // key row (K) / d row (V)
            int gc  = (seg & 7) ^ (row & 7);       // swizzled global 16B chunk
            async_load16(Kp + (size_t)(t0 + row) * HD + gc * 8, &Ks[b][seg * 8]);
            async_load16(Vp + (size_t)row * TT + t0 + gc * 8, &Vs[b][seg * 8]);
        }
    };

    stage(0, 0);

    const float C1 = 0.18033688f;    // 0.125 * log2(e)
    const float C2 = -11.5415603f;   // -8 * log2(e)

    for (int it = 0; it < niters; ++it) {
        __syncthreads();               // buf it&1 staged; prior buf free
        const bf16* Kb = &Ks[it & 1][0];
        const bf16* Vb = &Vs[it & 1][0];
        if (it + 1 < niters) stage(it + 1, (it + 1) & 1);

        const int t0 = it * 64;
        const int kbase = kh * 32;                         // wave key offset
        // wave-uniform: skip if this wave's keys are all masked for all its q
        if (t0 + kbase > qw + 31 + OFFS) continue;
        const bool full = (t0 + kbase + 31 <= qw + OFFS);  // no masking needed

        // ---- S^T = K·Q^T : 2 key-subtiles of 16 x 2 q-subtiles ----
        // C layout: row = key kbase+kt*16+quad*4+r, col = q = qs*16+l16
        f32x4 s[2][2];
#pragma unroll
        for (int kt = 0; kt < 2; ++kt) {
            int row = kbase + kt * 16 + l16;
            int swz = row & 7;
            bf16x8 ka = *(const bf16x8*)(Kb + (row * 8 + (quad ^ swz)) * 8);
            bf16x8 kb = *(const bf16x8*)(Kb + (row * 8 + ((4 + quad) ^ swz)) * 8);
#pragma unroll
            for (int qs = 0; qs < 2; ++qs) {
                f32x4 z = {0.f, 0.f, 0.f, 0.f};
                z = mfma16(ka, qf[qs][0], z);
                z = mfma16(kb, qf[qs][1], z);
                s[kt][qs] = z;
            }
        }

        // ---- fixed-max softmax, in-register ----
        f32x4 p[2][2];
        if (full) {
#pragma unroll
            for (int kt = 0; kt < 2; ++kt)
#pragma unroll
                for (int qs = 0; qs < 2; ++qs)
#pragma unroll
                    for (int r = 0; r < 4; ++r)
                        p[kt][qs][r] = __builtin_amdgcn_exp2f(fmaf(s[kt][qs][r], C1, C2));
        } else {
#pragma unroll
            for (int qs = 0; qs < 2; ++qs) {
                const int qlim = qw + qs * 16 + l16 + OFFS - t0;  // local key bound
#pragma unroll
                for (int kt = 0; kt < 2; ++kt)
#pragma unroll
                    for (int r = 0; r < 4; ++r) {
                        int tl = kbase + kt * 16 + quad * 4 + r;
                        float e = __builtin_amdgcn_exp2f(fmaf(s[kt][qs][r], C1, C2));
                        p[kt][qs][r] = (tl <= qlim) ? e : 0.f;
                    }
            }
        }
#pragma unroll
        for (int qs = 0; qs < 2; ++qs)
#pragma unroll
            for (int kt = 0; kt < 2; ++kt)
                lsum[qs] += (p[kt][qs][0] + p[kt][qs][1]) + (p[kt][qs][2] + p[kt][qs][3]);

        // ---- P^T as B-frags; k slot (quad,j): key kbase+quad*4+j (j<4),
        //      kbase+16+quad*4+(j-4) (j>=4) — permuted k-order ----
        bf16x8 pf[2];
#pragma unroll
        for (int qs = 0; qs < 2; ++qs)
#pragma unroll
            for (int j = 0; j < 4; ++j) {
                pf[qs][j]     = (bf16)p[0][qs][j];
                pf[qs][4 + j] = (bf16)p[1][qs][j];
            }

        // ---- O^T += V^T·P^T with the SAME k-permutation on the A-operand:
        //      slot j<4 -> key kbase+quad*4+j   = chunk kh*4+q1,   offset h4
        //      slot j>=4 -> key kbase+16+quad*4 = chunk kh*4+2+q1, offset h4
        const int q1 = quad >> 1;
        const int h4 = (quad & 1) * 4;   // bf16 units within 16B chunk
#pragma unroll
        for (int dt = 0; dt < 4; ++dt) {
            int row = dt * 16 + l16;
            int swz = row & 7;
            bf16x4 v0 = *(const bf16x4*)(Vb + (row * 8 + ((kh * 4 + q1) ^ swz)) * 8 + h4);
            bf16x4 v1 = *(const bf16x4*)(Vb + (row * 8 + ((kh * 4 + 2 + q1) ^ swz)) * 8 + h4);
            bf16x8 vf;
#pragma unroll
            for (int j = 0; j < 4; ++j) {
                vf[j] = v0[j]; vf[4 + j] = v1[j];
            }
#pragma unroll
            for (int qs = 0; qs < 2; ++qs)
                o[dt][qs] = mfma16(vf, pf[qs], o[dt][qs]);
        }
    }

    // ---- reduce lsum across quads (value for q = qs*16+l16) ----
#pragma unroll
    for (int qs = 0; qs < 2; ++qs) {
        lsum[qs] += __shfl_xor(lsum[qs], 16, 64);
        lsum[qs] += __shfl_xor(lsum[qs], 32, 64);
    }

    // ---- cross-wave (key-half) combine via LDS scratch ----
    __syncthreads();                       // all tile reads done; reuse Ks/Vs
    float* So = (float*)&Ks[0][0];         // 4096 floats: [32 elems][128 lanes]
    float* Sl = (float*)&Vs[0][0];         // 256 floats
    if (kh == 1) {
#pragma unroll
        for (int dt = 0; dt < 4; ++dt)
#pragma unroll
            for (int qs = 0; qs < 2; ++qs)
#pragma unroll
                for (int r = 0; r < 4; ++r)
                    So[(dt * 8 + qs * 4 + r) * 128 + qh * 64 + lane] = o[dt][qs][r];
#pragma unroll
        for (int qs = 0; qs < 2; ++qs)
            Sl[qs * 128 + qh * 64 + lane] = lsum[qs];
    }
    __syncthreads();
    if (kh == 1) return;

#pragma unroll
    for (int dt = 0; dt < 4; ++dt)
#pragma unroll
        for (int qs = 0; qs < 2; ++qs)
#pragma unroll
            for (int r = 0; r < 4; ++r)
                o[dt][qs][r] += So[(dt * 8 + qs * 4 + r) * 128 + qh * 64 + lane];
    float rl[2];
#pragma unroll
    for (int qs = 0; qs < 2; ++qs)
        rl[qs] = 1.f / (lsum[qs] + Sl[qs * 128 + qh * 64 + lane]);

    // o C layout: row = d_local = quad*4+r, col = q = qs*16+l16
    const int b = bh >> 4, h = bh & 15;
#pragma unroll
    for (int qs = 0; qs < 2; ++qs) {
        const int q = qw + qs * 16 + l16;
        bf16* op = Ob + (((size_t)(b * SS + q) * HH) + h) * HD;
#pragma unroll
        for (int dt = 0; dt < 4; ++dt) {
            bf16x4 w;
#pragma unroll
            for (int r = 0; r < 4; ++r) w[r] = (bf16)(o[dt][qs][r] * rl[qs]);
            *(bf16x4*)(op + dt * 16 + quad * 4) = w;
        }
    }
}

extern "C" void kernel_launch(void* const* d_in, const int* in_sizes, int n_in,
                              void* d_out, int out_size, void* d_ws, size_t ws_size,
                              hipStream_t stream) {
    const float* x   = (const float*)d_in[0];
    const float* ck  = (const float*)d_in[1];
    const float* cv  = (const float*)d_in[2];
    const float* Wq  = (const float*)d_in[3];
    const float* bq  = (const float*)d_in[4];
    const float* Wk  = (const float*)d_in[5];
    const float* bk  = (const float*)d_in[6];
    const float* Wv  = (const float*)d_in[7];
    const float* bv  = (const float*)d_in[8];
    const float* Wo  = (const float*)d_in[9];
    const float* bo  = (const float*)d_in[10];
    float* out = (float*)d_out;

    char* ws = (char*)d_ws;
    bf16* xb  = (bf16*)(ws);                   // [2048,1024]        4 MB
    bf16* wqb = (bf16*)(ws + ( 4u << 20));     // Wqkv [3072,1024] contiguous:
    bf16* wkb = (bf16*)(ws + ( 6u << 20));     //   wq 4-6, wk 6-8, wv 8-10 MB
    bf16* wvb = (bf16*)(ws + ( 8u << 20));
    bf16* wob = (bf16*)(ws + (10u << 20));
    bf16* Qb  = (bf16*)(ws + (12u << 20));     // [B,H,S,HD]         4 MB
    bf16* Kf  = (bf16*)(ws + (16u << 20));     // [B,H,TT,HD]        8 MB
    bf16* Vt  = (bf16*)(ws + (24u << 20));     // [B,H,HD,TT]        8 MB
    bf16* Ob  = (bf16*)(ws + (32u << 20));     // [B,S,H,HD]         4 MB

    // all conversions in one launch
    cvt_all<<<8704, 256, 0, stream>>>(x, xb, Wq, Wk, Wv, Wo, wqb, wkb, wvb, wob,
                                      ck, Kf, cv, Vt);

    // QKV projections: one fused GEMM over N=3072 (768 blocks = 3/CU exactly)
    gemm_nt<<<dim3(24, 32), 256, 0, stream>>>(xb, wqb, bq, bk, bv, bo,
                                              Qb, Kf, Vt, out, 0);
    // attention
    attn<<<512, 256, 0, stream>>>(Qb, Kf, Vt, Ob);
    // output projection (256 blocks = 1/CU exactly) -> fp32 d_out
    gemm_nt<<<dim3(8, 32), 256, 0, stream>>>(Ob, wob, bq, bk, bv, bo,
                                             Qb, Kf, Vt, out, 1);
}

// Round 7
// 159.451 us; speedup vs baseline: 1.0192x; 1.0192x over previous
//
#include <hip/hip_runtime.h>
#include <hip/hip_bf16.h>
#include <stdint.h>

typedef __bf16 bf16;
typedef __bf16 bf16x4 __attribute__((ext_vector_type(4)));
typedef __bf16 bf16x8 __attribute__((ext_vector_type(8)));
typedef float  f32x4  __attribute__((ext_vector_type(4)));

#define DEV __device__ __forceinline__

// ---- constants for this problem ----
#define BB 2
#define HH 16
#define SS 1024
#define DD 1024
#define HD 64
#define LC 1024
#define TT 2048   // LC + SS
#define OFFS 1024 // TT - SS (causal offset)

DEV f32x4 mfma16(bf16x8 a, bf16x8 b, f32x4 c) {
    return __builtin_amdgcn_mfma_f32_16x16x32_bf16(a, b, c, 0, 0, 0);
}

// async global->LDS, 16B per lane. LDS dest must be wave-uniform base + lane*16.
DEV void async_load16(const bf16* g, bf16* lds) {
    auto gp = reinterpret_cast<const __attribute__((address_space(1))) void*>(
        reinterpret_cast<uintptr_t>(g));
    auto lp = reinterpret_cast<__attribute__((address_space(3))) void*>(
        reinterpret_cast<uintptr_t>(lds));
    __builtin_amdgcn_global_load_lds(gp, lp, 16, 0, 0);
}

// ---------------------------------------------------------------------------
// One merged conversion kernel:
//   blocks [0,2048)        : x fp32 -> xb bf16
//   blocks [2048,6144)     : Wq/Wk/Wv/Wo fp32 -> bf16 (wq/wk/wv contiguous!)
//   blocks [6144,8192)     : cache_k -> Kfull rows [0,LC)
//   blocks [8192,8704)     : cache_v -> VT cols [0,LC) (64x64 transpose)
// ---------------------------------------------------------------------------
__global__ __launch_bounds__(256) void cvt_all(
    const float* __restrict__ x,  bf16* __restrict__ xb,
    const float* __restrict__ w0, const float* __restrict__ w1,
    const float* __restrict__ w2, const float* __restrict__ w3,
    bf16* __restrict__ d0, bf16* __restrict__ d1,
    bf16* __restrict__ d2, bf16* __restrict__ d3,
    const float* __restrict__ ck, bf16* __restrict__ Kf,
    const float* __restrict__ cv, bf16* __restrict__ Vt) {
    __shared__ float tile[64][65];
    const int bid = blockIdx.x;
    const int tid = threadIdx.x;
    if (bid < 8192) {
        const float* s;
        bf16* d;
        int i;
        if (bid < 2048) {                       // x
            s = x; d = xb; i = bid * 256 + tid;
        } else if (bid < 6144) {                // weights
            int which = (bid - 2048) >> 10;
            s = which == 0 ? w0 : which == 1 ? w1 : which == 2 ? w2 : w3;
            d = which == 0 ? d0 : which == 1 ? d1 : which == 2 ? d2 : d3;
            i = ((bid - 2048) & 1023) * 256 + tid;
        } else {                                // cache_k (with row re-base)
            int ii = (bid - 6144) * 256 + tid;
            int bh  = ii >> 14;                 // 16384 float4 per bh
            int rem = ii & 16383;
            float4 v = ((const float4*)ck)[ii];
            bf16x4 o;
            o[0] = (bf16)v.x; o[1] = (bf16)v.y; o[2] = (bf16)v.z; o[3] = (bf16)v.w;
            ((bf16x4*)(Kf + (size_t)bh * TT * HD))[rem] = o;
            return;
        }
        float4 v = ((const float4*)s)[i];
        bf16x4 o;
        o[0] = (bf16)v.x; o[1] = (bf16)v.y; o[2] = (bf16)v.z; o[3] = (bf16)v.w;
        ((bf16x4*)d)[i] = o;
    } else {                                    // cache_v transpose
        int rem = bid - 8192;
        int bh = rem >> 4;
        int t0 = (rem & 15) * 64;
        int c4 = (tid & 15) * 4;
        int rr = tid >> 4;
        const float* src = cv + ((size_t)bh * LC + t0) * HD;
#pragma unroll
        for (int p = 0; p < 4; ++p) {
            int t = rr + p * 16;
            float4 v = *(const float4*)(src + (size_t)t * HD + c4);
            tile[c4 + 0][t] = v.x; tile[c4 + 1][t] = v.y;
            tile[c4 + 2][t] = v.z; tile[c4 + 3][t] = v.w;
        }
        __syncthreads();
        bf16* dst = Vt + (size_t)bh * HD * TT + t0;
#pragma unroll
        for (int p = 0; p < 4; ++p) {
            int d = rr + p * 16;
            int tc = (tid & 15) * 4;
            bf16x4 o;
            o[0] = (bf16)tile[d][tc + 0]; o[1] = (bf16)tile[d][tc + 1];
            o[2] = (bf16)tile[d][tc + 2]; o[3] = (bf16)tile[d][tc + 3];
            *(bf16x4*)(dst + (size_t)d * TT + tc) = o;
        }
    }
}

// ---------------------------------------------------------------------------
// NT GEMM v2: Y[m,n] = sum_k A[m,k] * W[n,k] + bias[n].  K = 1024.
//   BM=64, BN=128, BK=64; 4 waves, wave tile 64x32 (n-split).
//   Double-buffered LDS, one barrier per K-step, global_load_lds(16B)
//   prefetch of tile k+1 under compute of tile k, XOR chunk swizzle.
// ---------------------------------------------------------------------------
__global__ __launch_bounds__(256) void gemm_nt(
    const bf16* __restrict__ A, const bf16* __restrict__ W,
    const float* __restrict__ bq, const float* __restrict__ bk,
    const float* __restrict__ bv, const float* __restrict__ bo,
    bf16* __restrict__ Qb, bf16* __restrict__ Kf, bf16* __restrict__ Vt,
    float* __restrict__ Out, int is_oproj) {
    const int tid  = threadIdx.x;
    const int wv   = tid >> 6;
    const int lane = tid & 63;
    const int l16  = lane & 15;
    const int quad = lane >> 4;
    const int m0 = blockIdx.y * 64;
    const int n0 = blockIdx.x * 128;
    const int mode = is_oproj ? 3 : (n0 >> 10);
    const float* bias = (mode == 0) ? bq : (mode == 1) ? bk : (mode == 2) ? bv : bo;

    __shared__ __align__(16) bf16 As[2][64 * 64];
    __shared__ __align__(16) bf16 Bs[2][128 * 64];

    f32x4 acc[4][2];
#pragma unroll
    for (int i = 0; i < 4; ++i)
#pragma unroll
        for (int j = 0; j < 2; ++j) {
            f32x4 z = {0.f, 0.f, 0.f, 0.f};
            acc[i][j] = z;
        }

    // stage K-step k0 into buffer b (A: 512 chunks, B: 1024 chunks, XOR swizzle)
    auto stage = [&](int k0, int b) {
#pragma unroll
        for (int k = 0; k < 2; ++k) {
            int seg = k * 256 + tid;
            int row = seg >> 3;
            int c   = (seg & 7) ^ (row & 7);
            async_load16(A + (size_t)(m0 + row) * 1024 + k0 + c * 8, &As[b][seg * 8]);
        }
#pragma unroll
        for (int k = 0; k < 4; ++k) {
            int seg = k * 256 + tid;
            int row = seg >> 3;
            int c   = (seg & 7) ^ (row & 7);
            async_load16(W + (size_t)(n0 + row) * 1024 + k0 + c * 8, &Bs[b][seg * 8]);
        }
    };

    stage(0, 0);

    for (int it = 0; it < 16; ++it) {
        __syncthreads();               // buf it&1 staged; prior buf free
        const bf16* Ab = &As[it & 1][0];
        const bf16* Bb = &Bs[it & 1][0];
        if (it + 1 < 16) stage((it + 1) * 64, (it + 1) & 1);

#pragma unroll
        for (int kk = 0; kk < 2; ++kk) {
            bf16x8 af[4], bfr[2];
#pragma unroll
            for (int i = 0; i < 4; ++i) {
                int row = i * 16 + l16;
                int slot = (kk * 4 + quad) ^ (row & 7);
                af[i] = *(const bf16x8*)(Ab + (row * 8 + slot) * 8);
            }
#pragma unroll
            for (int j = 0; j < 2; ++j) {
                int row = wv * 32 + j * 16 + l16;
                int slot = (kk * 4 + quad) ^ (row & 7);
                bfr[j] = *(const bf16x8*)(Bb + (row * 8 + slot) * 8);
            }
#pragma unroll
            for (int i = 0; i < 4; ++i)
#pragma unroll
                for (int j = 0; j < 2; ++j)
                    acc[i][j] = mfma16(af[i], bfr[j], acc[i][j]);
        }
    }

    // epilogue: C layout col = l16 (n), row = quad*4 + r (m)
#pragma unroll
    for (int i = 0; i < 4; ++i) {
#pragma unroll
        for (int j = 0; j < 2; ++j) {
            int n = n0 + wv * 32 + j * 16 + l16;
            float bval = bias[n & 1023];
#pragma unroll
            for (int r = 0; r < 4; ++r) {
                int m = m0 + i * 16 + quad * 4 + r;
                float v = acc[i][j][r] + bval;
                if (mode == 3) {
                    Out[(size_t)m * 1024 + n] = v;
                } else {
                    int b = m >> 10, s = m & 1023;
                    int h = (n & 1023) >> 6, d = n & 63;
                    int bh = b * HH + h;
                    if (mode == 0)
                        Qb[((size_t)bh * SS + s) * HD + d] = (bf16)v;
                    else if (mode == 1)
                        Kf[((size_t)bh * TT + LC + s) * HD + d] = (bf16)v;
                    else
                        Vt[((size_t)bh * HD + d) * TT + LC + s] = (bf16)v;
                }
            }
        }
    }
}

// ---------------------------------------------------------------------------
// Flash attention v6: 128-key tiles (halves barrier count; compute per barrier
// now covers the global_load_lds latency, which R5 showed to be the real
// bottleneck — not LDS BW). Keeps: S^T formulation, fixed-max softmax, 2x2
// (q x key-half) wave split (kbase = kh*64), permuted-k PV (R5 fix), additive
// cross-wave combine. LDS = 2 x (16K + 16K) = 64 KB -> 2 blocks/CU (128/160).
//   K tile: 128 keys x 64 d, row = key, 8 chunks/row, swizzle c^(row&7)
//   V tile: 64 d x 128 keys, row = d, 16 chunks/row, swizzle c^(row&15)
// ---------------------------------------------------------------------------
__global__ __launch_bounds__(256) void attn(const bf16* __restrict__ Qb,
                                            const bf16* __restrict__ Kf,
                                            const bf16* __restrict__ Vt,
                                            bf16* __restrict__ Ob) {
    const int i = blockIdx.x;
    const int bh = i & 31;
    const int qblk = (i < 256) ? (15 - (i >> 5)) : ((i >> 5) - 8);
    const int tid  = threadIdx.x;
    const int wv   = tid >> 6;
    const int qh   = wv & 1;
    const int kh   = wv >> 1;
    const int lane = tid & 63;
    const int l16  = lane & 15;
    const int quad = lane >> 4;
    const int qb   = qblk * 64;            // block q base
    const int qw   = qb + qh * 32;         // wave q base (32 rows)
    const int kbase = kh * 64;             // wave key offset within 128-tile

    const bf16* Qp = Qb + ((size_t)bh * SS + qw) * HD;
    const bf16* Kp = Kf + (size_t)bh * TT * HD;
    const bf16* Vp = Vt + (size_t)bh * HD * TT;

    __shared__ __align__(16) bf16 Ks[2][128 * 64];
    __shared__ __align__(16) bf16 Vs[2][64 * 128];

    // Q as B-operand: qf[qs][dc] = B[k=d=dc*32+quad*8+j][n=q=qs*16+l16]
    bf16x8 qf[2][2];
#pragma unroll
    for (int qs = 0; qs < 2; ++qs)
#pragma unroll
        for (int dc = 0; dc < 2; ++dc)
            qf[qs][dc] = *(const bf16x8*)(Qp + (qs * 16 + l16) * HD + dc * 32 + quad * 8);

    float lsum[2] = {0.f, 0.f};
    f32x4 o[4][2];
#pragma unroll
    for (int dt = 0; dt < 4; ++dt)
#pragma unroll
        for (int qs = 0; qs < 2; ++qs) {
            f32x4 z = {0.f, 0.f, 0.f, 0.f};
            o[dt][qs] = z;
        }

    const int niters = qblk / 2 + 9;   // ceil((qb + 64 + OFFS) / 128)

    // stage 128-key tile into buffer b; XOR chunk swizzle on global address
    auto stage = [&](int tile, int b) {
        const int t0 = tile * 128;
#pragma unroll
        for (int j = 0; j < 4; ++j) {
            int seg = j * 256 + tid;               // 0..1023
            int krow = seg >> 3;                   // key 0..127
            int kc   = (seg & 7) ^ (krow & 7);
            async_load16(Kp + (size_t)(t0 + krow) * HD + kc * 8, &Ks[b][seg * 8]);
            int drow = seg >> 4;                   // d 0..63
            int tc   = (seg & 15) ^ (drow & 15);
            async_load16(Vp + (size_t)drow * TT + t0 + tc * 8, &Vs[b][seg * 8]);
        }
    };

    stage(0, 0);

    const float C1 = 0.18033688f;    // 0.125 * log2(e)
    const float C2 = -11.5415603f;   // -8 * log2(e)

    for (int it = 0; it < niters; ++it) {
        __syncthreads();               // buf it&1 staged; prior buf free
        const bf16* Kb = &Ks[it & 1][0];
        const bf16* Vb = &Vs[it & 1][0];
        if (it + 1 < niters) stage(it + 1, (it + 1) & 1);

        const int t0 = it * 128;
        // wave-uniform: skip if this wave's 64 keys are all masked for all its q
        if (t0 + kbase > qw + 31 + OFFS) continue;
        const bool full = (t0 + kbase + 63 <= qw + OFFS);  // no masking needed

        // ---- S^T = K·Q^T : 4 key-subtiles of 16 x 2 q-subtiles ----
        // C layout: row = key kbase+kt*16+quad*4+r, col = q = qs*16+l16
        f32x4 s[4][2];
#pragma unroll
        for (int kt = 0; kt < 4; ++kt) {
            int row = kbase + kt * 16 + l16;
            int swz = row & 7;
            bf16x8 ka = *(const bf16x8*)(Kb + (row * 8 + (quad ^ swz)) * 8);
            bf16x8 kb = *(const bf16x8*)(Kb + (row * 8 + ((4 + quad) ^ swz)) * 8);
#pragma unroll
            for (int qs = 0; qs < 2; ++qs) {
                f32x4 z = {0.f, 0.f, 0.f, 0.f};
                z = mfma16(ka, qf[qs][0], z);
                z = mfma16(kb, qf[qs][1], z);
                s[kt][qs] = z;
            }
        }

        // ---- fixed-max softmax, in-register ----
        f32x4 p[4][2];
        if (full) {
#pragma unroll
            for (int kt = 0; kt < 4; ++kt)
#pragma unroll
                for (int qs = 0; qs < 2; ++qs)
#pragma unroll
                    for (int r = 0; r < 4; ++r)
                        p[kt][qs][r] = __builtin_amdgcn_exp2f(fmaf(s[kt][qs][r], C1, C2));
        } else {
#pragma unroll
            for (int qs = 0; qs < 2; ++qs) {
                const int qlim = qw + qs * 16 + l16 + OFFS - t0;  // local key bound
#pragma unroll
                for (int kt = 0; kt < 4; ++kt)
#pragma unroll
                    for (int r = 0; r < 4; ++r) {
                        int tl = kbase + kt * 16 + quad * 4 + r;
                        float e = __builtin_amdgcn_exp2f(fmaf(s[kt][qs][r], C1, C2));
                        p[kt][qs][r] = (tl <= qlim) ? e : 0.f;
                    }
            }
        }
#pragma unroll
        for (int qs = 0; qs < 2; ++qs)
#pragma unroll
            for (int kt = 0; kt < 4; ++kt)
                lsum[qs] += (p[kt][qs][0] + p[kt][qs][1]) + (p[kt][qs][2] + p[kt][qs][3]);

        // ---- P^T as B-frags (2 key-frags of 32); permuted k-order:
        //      frag kf, slot j<4  -> key kbase+kf*32+quad*4+j
        //      frag kf, slot j>=4 -> key kbase+kf*32+16+quad*4+(j-4)
        bf16x8 pf[2][2];
#pragma unroll
        for (int kf = 0; kf < 2; ++kf)
#pragma unroll
            for (int qs = 0; qs < 2; ++qs)
#pragma unroll
                for (int j = 0; j < 4; ++j) {
                    pf[kf][qs][j]     = (bf16)p[kf * 2][qs][j];
                    pf[kf][qs][4 + j] = (bf16)p[kf * 2 + 1][qs][j];
                }

        // ---- O^T += V^T·P^T with SAME k-permutation on the A-operand:
        //      chunk index for key k is k>>3; kbase>>3 = kh*8
        //      slot j<4  -> chunk kh*8 + kf*4 + q1,     offset h4
        //      slot j>=4 -> chunk kh*8 + kf*4 + 2 + q1, offset h4
        const int q1 = quad >> 1;
        const int h4 = (quad & 1) * 4;   // bf16 units within 16B chunk
#pragma unroll
        for (int dt = 0; dt < 4; ++dt) {
            int row = dt * 16 + l16;
            int swz = row & 15;
#pragma unroll
            for (int kf = 0; kf < 2; ++kf) {
                int c0 = kh * 8 + kf * 4 + q1;
                bf16x4 v0 = *(const bf16x4*)(Vb + (row * 16 + (c0 ^ swz)) * 8 + h4);
                bf16x4 v1 = *(const bf16x4*)(Vb + (row * 16 + ((c0 + 2) ^ swz)) * 8 + h4);
                bf16x8 vf;
#pragma unroll
                for (int j = 0; j < 4; ++j) {
                    vf[j] = v0[j]; vf[4 + j] = v1[j];
                }
#pragma unroll
                for (int qs = 0; qs < 2; ++qs)
                    o[dt][qs] = mfma16(vf, pf[kf][qs], o[dt][qs]);
            }
        }
    }

    // ---- reduce lsum across quads (value for q = qs*16+l16) ----
#pragma unroll
    for (int qs = 0; qs < 2; ++qs) {
        lsum[qs] += __shfl_xor(lsum[qs], 16, 64);
        lsum[qs] += __shfl_xor(lsum[qs], 32, 64);
    }

    // ---- cross-wave (key-half) combine via LDS scratch ----
    __syncthreads();                       // all tile reads done; reuse Ks/Vs
    float* So = (float*)&Ks[0][0];         // 4096 floats: [32 elems][128 lanes]
    float* Sl = (float*)&Vs[0][0];         // 256 floats
    if (kh == 1) {
#pragma unroll
        for (int dt = 0; dt < 4; ++dt)
#pragma unroll
            for (int qs = 0; qs < 2; ++qs)
#pragma unroll
                for (int r = 0; r < 4; ++r)
                    So[(dt * 8 + qs * 4 + r) * 128 + qh * 64 + lane] = o[dt][qs][r];
#pragma unroll
        for (int qs = 0; qs < 2; ++qs)
            Sl[qs * 128 + qh * 64 + lane] = lsum[qs];
    }
    __syncthreads();
    if (kh == 1) return;

#pragma unroll
    for (int dt = 0; dt < 4; ++dt)
#pragma unroll
        for (int qs = 0; qs < 2; ++qs)
#pragma unroll
            for (int r = 0; r < 4; ++r)
                o[dt][qs][r] += So[(dt * 8 + qs * 4 + r) * 128 + qh * 64 + lane];
    float rl[2];
#pragma unroll
    for (int qs = 0; qs < 2; ++qs)
        rl[qs] = 1.f / (lsum[qs] + Sl[qs * 128 + qh * 64 + lane]);

    // o C layout: row = d_local = quad*4+r, col = q = qs*16+l16
    const int b = bh >> 4, h = bh & 15;
#pragma unroll
    for (int qs = 0; qs < 2; ++qs) {
        const int q = qw + qs * 16 + l16;
        bf16* op = Ob + (((size_t)(b * SS + q) * HH) + h) * HD;
#pragma unroll
        for (int dt = 0; dt < 4; ++dt) {
            bf16x4 w;
#pragma unroll
            for (int r = 0; r < 4; ++r) w[r] = (bf16)(o[dt][qs][r] * rl[qs]);
            *(bf16x4*)(op + dt * 16 + quad * 4) = w;
        }
    }
}

extern "C" void kernel_launch(void* const* d_in, const int* in_sizes, int n_in,
                              void* d_out, int out_size, void* d_ws, size_t ws_size,
                              hipStream_t stream) {
    const float* x   = (const float*)d_in[0];
    const float* ck  = (const float*)d_in[1];
    const float* cv  = (const float*)d_in[2];
    const float* Wq  = (const float*)d_in[3];
    const float* bq  = (const float*)d_in[4];
    const float* Wk  = (const float*)d_in[5];
    const float* bk  = (const float*)d_in[6];
    const float* Wv  = (const float*)d_in[7];
    const float* bv  = (const float*)d_in[8];
    const float* Wo  = (const float*)d_in[9];
    const float* bo  = (const float*)d_in[10];
    float* out = (float*)d_out;

    char* ws = (char*)d_ws;
    bf16* xb  = (bf16*)(ws);                   // [2048,1024]        4 MB
    bf16* wqb = (bf16*)(ws + ( 4u << 20));     // Wqkv [3072,1024] contiguous:
    bf16* wkb = (bf16*)(ws + ( 6u << 20));     //   wq 4-6, wk 6-8, wv 8-10 MB
    bf16* wvb = (bf16*)(ws + ( 8u << 20));
    bf16* wob = (bf16*)(ws + (10u << 20));
    bf16* Qb  = (bf16*)(ws + (12u << 20));     // [B,H,S,HD]         4 MB
    bf16* Kf  = (bf16*)(ws + (16u << 20));     // [B,H,TT,HD]        8 MB
    bf16* Vt  = (bf16*)(ws + (24u << 20));     // [B,H,HD,TT]        8 MB
    bf16* Ob  = (bf16*)(ws + (32u << 20));     // [B,S,H,HD]         4 MB

    // all conversions in one launch
    cvt_all<<<8704, 256, 0, stream>>>(x, xb, Wq, Wk, Wv, Wo, wqb, wkb, wvb, wob,
                                      ck, Kf, cv, Vt);

    // QKV projections: one fused GEMM over N=3072 (768 blocks = 3/CU exactly)
    gemm_nt<<<dim3(24, 32), 256, 0, stream>>>(xb, wqb, bq, bk, bv, bo,
                                              Qb, Kf, Vt, out, 0);
    // attention
    attn<<<512, 256, 0, stream>>>(Qb, Kf, Vt, Ob);
    // output projection (256 blocks = 1/CU exactly) -> fp32 d_out
    gemm_nt<<<dim3(8, 32), 256, 0, stream>>>(Ob, wob, bq, bk, bv, bo,
                                             Qb, Kf, Vt, out, 1);
}

// Round 8
// 157.936 us; speedup vs baseline: 1.0290x; 1.0096x over previous
//
#include <hip/hip_runtime.h>
#include <hip/hip_bf16.h>
#include <stdint.h>

typedef __bf16 bf16;
typedef __bf16 bf16x4 __attribute__((ext_vector_type(4)));
typedef __bf16 bf16x8 __attribute__((ext_vector_type(8)));
typedef float  f32x4  __attribute__((ext_vector_type(4)));

#define DEV __device__ __forceinline__

// ---- constants for this problem ----
#define BB 2
#define HH 16
#define SS 1024
#define DD 1024
#define HD 64
#define LC 1024
#define TT 2048   // LC + SS
#define OFFS 1024 // TT - SS (causal offset)

DEV f32x4 mfma16(bf16x8 a, bf16x8 b, f32x4 c) {
    return __builtin_amdgcn_mfma_f32_16x16x32_bf16(a, b, c, 0, 0, 0);
}

// async global->LDS, 16B per lane. LDS dest must be wave-uniform base + lane*16.
DEV void async_load16(const bf16* g, bf16* lds) {
    auto gp = reinterpret_cast<const __attribute__((address_space(1))) void*>(
        reinterpret_cast<uintptr_t>(g));
    auto lp = reinterpret_cast<__attribute__((address_space(3))) void*>(
        reinterpret_cast<uintptr_t>(lds));
    __builtin_amdgcn_global_load_lds(gp, lp, 16, 0, 0);
}

DEV bf16x8 cvt8(float4 a, float4 b) {
    bf16x8 o;
    o[0] = (bf16)a.x; o[1] = (bf16)a.y; o[2] = (bf16)a.z; o[3] = (bf16)a.w;
    o[4] = (bf16)b.x; o[5] = (bf16)b.y; o[6] = (bf16)b.z; o[7] = (bf16)b.w;
    return o;
}

// ---------------------------------------------------------------------------
// Merged conversion kernel, 8 elems/lane (2x float4 read -> 16B bf16x8 store):
//   blocks [0,1024)     : x fp32 -> xb bf16            (2M elems)
//   blocks [1024,3072)  : Wq/Wk/Wv/Wo fp32 -> bf16     (512 blocks each)
//   blocks [3072,4096)  : cache_k -> Kfull rows [0,LC)
//   blocks [4096,4608)  : cache_v -> VT cols [0,LC) (64x64 transpose)
// ---------------------------------------------------------------------------
__global__ __launch_bounds__(256) void cvt_all(
    const float* __restrict__ x,  bf16* __restrict__ xb,
    const float* __restrict__ w0, const float* __restrict__ w1,
    const float* __restrict__ w2, const float* __restrict__ w3,
    bf16* __restrict__ d0, bf16* __restrict__ d1,
    bf16* __restrict__ d2, bf16* __restrict__ d3,
    const float* __restrict__ ck, bf16* __restrict__ Kf,
    const float* __restrict__ cv, bf16* __restrict__ Vt) {
    __shared__ float tile[64][65];
    const int bid = blockIdx.x;
    const int tid = threadIdx.x;
    if (bid < 4096) {
        const float* s;
        bf16* d;
        int i;   // index in float4 units (2 per lane)
        if (bid < 1024) {                       // x
            s = x; d = xb; i = bid * 512 + tid * 2;
        } else if (bid < 3072) {                // weights
            int which = (bid - 1024) >> 9;
            s = which == 0 ? w0 : which == 1 ? w1 : which == 2 ? w2 : w3;
            d = which == 0 ? d0 : which == 1 ? d1 : which == 2 ? d2 : d3;
            i = ((bid - 1024) & 511) * 512 + tid * 2;
        } else {                                // cache_k (with row re-base)
            int ii = (bid - 3072) * 512 + tid * 2;     // float4 index
            int bh  = ii >> 14;                        // 16384 float4 per bh
            int rem = ii & 16383;
            float4 a = ((const float4*)ck)[ii];
            float4 b = ((const float4*)ck)[ii + 1];
            ((bf16x8*)(Kf + (size_t)bh * TT * HD))[rem >> 1] = cvt8(a, b);
            return;
        }
        float4 a = ((const float4*)s)[i];
        float4 b = ((const float4*)s)[i + 1];
        ((bf16x8*)d)[i >> 1] = cvt8(a, b);
    } else {                                    // cache_v transpose
        int rem = bid - 4096;
        int bh = rem >> 4;
        int t0 = (rem & 15) * 64;
        int c4 = (tid & 15) * 4;
        int rr = tid >> 4;
        const float* src = cv + ((size_t)bh * LC + t0) * HD;
#pragma unroll
        for (int p = 0; p < 4; ++p) {
            int t = rr + p * 16;
            float4 v = *(const float4*)(src + (size_t)t * HD + c4);
            tile[c4 + 0][t] = v.x; tile[c4 + 1][t] = v.y;
            tile[c4 + 2][t] = v.z; tile[c4 + 3][t] = v.w;
        }
        __syncthreads();
        bf16* dst = Vt + (size_t)bh * HD * TT + t0;
#pragma unroll
        for (int p = 0; p < 4; ++p) {
            int d = rr + p * 16;
            int tc = (tid & 15) * 4;
            bf16x4 o;
            o[0] = (bf16)tile[d][tc + 0]; o[1] = (bf16)tile[d][tc + 1];
            o[2] = (bf16)tile[d][tc + 2]; o[3] = (bf16)tile[d][tc + 3];
            *(bf16x4*)(dst + (size_t)d * TT + tc) = o;
        }
    }
}

// ---------------------------------------------------------------------------
// QKV NT GEMM: Y[m,n] = sum_k A[m,k] * Wqkv[n,k] + bias[n].  K = 1024, N=3072.
//   BM=64, BN=128, BK=64; 4 waves, wave tile 64x32 (n-split).
//   Double-buffered LDS, one barrier per K-step, global_load_lds(16B)
//   prefetch of tile k+1 under compute of tile k, XOR chunk swizzle.
//   mode = n0>>10 routes output (0:Qb, 1:Kf rows LC+, 2:Vt cols LC+).
// ---------------------------------------------------------------------------
__global__ __launch_bounds__(256) void gemm_nt(
    const bf16* __restrict__ A, const bf16* __restrict__ W,
    const float* __restrict__ bq, const float* __restrict__ bk,
    const float* __restrict__ bv,
    bf16* __restrict__ Qb, bf16* __restrict__ Kf, bf16* __restrict__ Vt) {
    const int tid  = threadIdx.x;
    const int wv   = tid >> 6;
    const int lane = tid & 63;
    const int l16  = lane & 15;
    const int quad = lane >> 4;
    const int m0 = blockIdx.y * 64;
    const int n0 = blockIdx.x * 128;
    const int mode = n0 >> 10;
    const float* bias = (mode == 0) ? bq : (mode == 1) ? bk : bv;

    __shared__ __align__(16) bf16 As[2][64 * 64];
    __shared__ __align__(16) bf16 Bs[2][128 * 64];

    f32x4 acc[4][2];
#pragma unroll
    for (int i = 0; i < 4; ++i)
#pragma unroll
        for (int j = 0; j < 2; ++j) {
            f32x4 z = {0.f, 0.f, 0.f, 0.f};
            acc[i][j] = z;
        }

    // stage K-step k0 into buffer b (A: 512 chunks, B: 1024 chunks, XOR swizzle)
    auto stage = [&](int k0, int b) {
#pragma unroll
        for (int k = 0; k < 2; ++k) {
            int seg = k * 256 + tid;
            int row = seg >> 3;
            int c   = (seg & 7) ^ (row & 7);
            async_load16(A + (size_t)(m0 + row) * 1024 + k0 + c * 8, &As[b][seg * 8]);
        }
#pragma unroll
        for (int k = 0; k < 4; ++k) {
            int seg = k * 256 + tid;
            int row = seg >> 3;
            int c   = (seg & 7) ^ (row & 7);
            async_load16(W + (size_t)(n0 + row) * 1024 + k0 + c * 8, &Bs[b][seg * 8]);
        }
    };

    stage(0, 0);

    for (int it = 0; it < 16; ++it) {
        __syncthreads();               // buf it&1 staged; prior buf free
        const bf16* Ab = &As[it & 1][0];
        const bf16* Bb = &Bs[it & 1][0];
        if (it + 1 < 16) stage((it + 1) * 64, (it + 1) & 1);

#pragma unroll
        for (int kk = 0; kk < 2; ++kk) {
            bf16x8 af[4], bfr[2];
#pragma unroll
            for (int i = 0; i < 4; ++i) {
                int row = i * 16 + l16;
                int slot = (kk * 4 + quad) ^ (row & 7);
                af[i] = *(const bf16x8*)(Ab + (row * 8 + slot) * 8);
            }
#pragma unroll
            for (int j = 0; j < 2; ++j) {
                int row = wv * 32 + j * 16 + l16;
                int slot = (kk * 4 + quad) ^ (row & 7);
                bfr[j] = *(const bf16x8*)(Bb + (row * 8 + slot) * 8);
            }
#pragma unroll
            for (int i = 0; i < 4; ++i)
#pragma unroll
                for (int j = 0; j < 2; ++j)
                    acc[i][j] = mfma16(af[i], bfr[j], acc[i][j]);
        }
    }

    // epilogue: C layout col = l16 (n), row = quad*4 + r (m)
#pragma unroll
    for (int i = 0; i < 4; ++i) {
#pragma unroll
        for (int j = 0; j < 2; ++j) {
            int n = n0 + wv * 32 + j * 16 + l16;
            float bval = bias[n & 1023];
#pragma unroll
            for (int r = 0; r < 4; ++r) {
                int m = m0 + i * 16 + quad * 4 + r;
                float v = acc[i][j][r] + bval;
                int b = m >> 10, s = m & 1023;
                int h = (n & 1023) >> 6, d = n & 63;
                int bh = b * HH + h;
                if (mode == 0)
                    Qb[((size_t)bh * SS + s) * HD + d] = (bf16)v;
                else if (mode == 1)
                    Kf[((size_t)bh * TT + LC + s) * HD + d] = (bf16)v;
                else
                    Vt[((size_t)bh * HD + d) * TT + LC + s] = (bf16)v;
            }
        }
    }
}

// ---------------------------------------------------------------------------
// Output projection GEMM: Out[m,n] = sum_k Ob[m,k] * Wo[n,k] + bo[n], fp32 out.
//   BM=32, BN=128 -> grid (8,64) = 512 blocks = 2/CU (was 1/CU): 2x TLP for
//   latency hiding. LDS 2x(4K+16K) = 40 KB. Wave tile 32x32, acc[2][2].
// ---------------------------------------------------------------------------
__global__ __launch_bounds__(256) void gemm_oproj(
    const bf16* __restrict__ A, const bf16* __restrict__ W,
    const float* __restrict__ bo, float* __restrict__ Out) {
    const int tid  = threadIdx.x;
    const int wv   = tid >> 6;
    const int lane = tid & 63;
    const int l16  = lane & 15;
    const int quad = lane >> 4;
    const int m0 = blockIdx.y * 32;
    const int n0 = blockIdx.x * 128;

    __shared__ __align__(16) bf16 As[2][32 * 64];
    __shared__ __align__(16) bf16 Bs[2][128 * 64];

    f32x4 acc[2][2];
#pragma unroll
    for (int i = 0; i < 2; ++i)
#pragma unroll
        for (int j = 0; j < 2; ++j) {
            f32x4 z = {0.f, 0.f, 0.f, 0.f};
            acc[i][j] = z;
        }

    auto stage = [&](int k0, int b) {
        {
            int seg = tid;                 // A: 256 chunks (32 rows x 8)
            int row = seg >> 3;
            int c   = (seg & 7) ^ (row & 7);
            async_load16(A + (size_t)(m0 + row) * 1024 + k0 + c * 8, &As[b][seg * 8]);
        }
#pragma unroll
        for (int k = 0; k < 4; ++k) {      // B: 1024 chunks (128 rows x 8)
            int seg = k * 256 + tid;
            int row = seg >> 3;
            int c   = (seg & 7) ^ (row & 7);
            async_load16(W + (size_t)(n0 + row) * 1024 + k0 + c * 8, &Bs[b][seg * 8]);
        }
    };

    stage(0, 0);

    for (int it = 0; it < 16; ++it) {
        __syncthreads();
        const bf16* Ab = &As[it & 1][0];
        const bf16* Bb = &Bs[it & 1][0];
        if (it + 1 < 16) stage((it + 1) * 64, (it + 1) & 1);

#pragma unroll
        for (int kk = 0; kk < 2; ++kk) {
            bf16x8 af[2], bfr[2];
#pragma unroll
            for (int i = 0; i < 2; ++i) {
                int row = i * 16 + l16;
                int slot = (kk * 4 + quad) ^ (row & 7);
                af[i] = *(const bf16x8*)(Ab + (row * 8 + slot) * 8);
            }
#pragma unroll
            for (int j = 0; j < 2; ++j) {
                int row = wv * 32 + j * 16 + l16;
                int slot = (kk * 4 + quad) ^ (row & 7);
                bfr[j] = *(const bf16x8*)(Bb + (row * 8 + slot) * 8);
            }
#pragma unroll
            for (int i = 0; i < 2; ++i)
#pragma unroll
                for (int j = 0; j < 2; ++j)
                    acc[i][j] = mfma16(af[i], bfr[j], acc[i][j]);
        }
    }

#pragma unroll
    for (int i = 0; i < 2; ++i) {
#pragma unroll
        for (int j = 0; j < 2; ++j) {
            int n = n0 + wv * 32 + j * 16 + l16;
            float bval = bo[n];
#pragma unroll
            for (int r = 0; r < 4; ++r) {
                int m = m0 + i * 16 + quad * 4 + r;
                Out[(size_t)m * 1024 + n] = acc[i][j][r] + bval;
            }
        }
    }
}

// ---------------------------------------------------------------------------
// Flash attention v6 (R6-verified) + heavy-first dispatch ordering:
// qblk = 15 - (i>>5): heaviest blocks dispatch first, lightest last -> greedy
// backfill minimizes the straggler tail (no same-CU pairing assumption).
// ---------------------------------------------------------------------------
__global__ __launch_bounds__(256) void attn(const bf16* __restrict__ Qb,
                                            const bf16* __restrict__ Kf,
                                            const bf16* __restrict__ Vt,
                                            bf16* __restrict__ Ob) {
    const int i = blockIdx.x;
    const int bh = i & 31;
    const int qblk = 15 - (i >> 5);
    const int tid  = threadIdx.x;
    const int wv   = tid >> 6;
    const int qh   = wv & 1;
    const int kh   = wv >> 1;
    const int lane = tid & 63;
    const int l16  = lane & 15;
    const int quad = lane >> 4;
    const int qb   = qblk * 64;            // block q base
    const int qw   = qb + qh * 32;         // wave q base (32 rows)
    const int kbase = kh * 64;             // wave key offset within 128-tile

    const bf16* Qp = Qb + ((size_t)bh * SS + qw) * HD;
    const bf16* Kp = Kf + (size_t)bh * TT * HD;
    const bf16* Vp = Vt + (size_t)bh * HD * TT;

    __shared__ __align__(16) bf16 Ks[2][128 * 64];
    __shared__ __align__(16) bf16 Vs[2][64 * 128];

    // Q as B-operand: qf[qs][dc] = B[k=d=dc*32+quad*8+j][n=q=qs*16+l16]
    bf16x8 qf[2][2];
#pragma unroll
    for (int qs = 0; qs < 2; ++qs)
#pragma unroll
        for (int dc = 0; dc < 2; ++dc)
            qf[qs][dc] = *(const bf16x8*)(Qp + (qs * 16 + l16) * HD + dc * 32 + quad * 8);

    float lsum[2] = {0.f, 0.f};
    f32x4 o[4][2];
#pragma unroll
    for (int dt = 0; dt < 4; ++dt)
#pragma unroll
        for (int qs = 0; qs < 2; ++qs) {
            f32x4 z = {0.f, 0.f, 0.f, 0.f};
            o[dt][qs] = z;
        }

    const int niters = qblk / 2 + 9;   // ceil((qb + 64 + OFFS) / 128)

    // stage 128-key tile into buffer b; XOR chunk swizzle on global address
    auto stage = [&](int tile, int b) {
        const int t0 = tile * 128;
#pragma unroll
        for (int j = 0; j < 4; ++j) {
            int seg = j * 256 + tid;               // 0..1023
            int krow = seg >> 3;                   // key 0..127
            int kc   = (seg & 7) ^ (krow & 7);
            async_load16(Kp + (size_t)(t0 + krow) * HD + kc * 8, &Ks[b][seg * 8]);
            int drow = seg >> 4;                   // d 0..63
            int tc   = (seg & 15) ^ (drow & 15);
            async_load16(Vp + (size_t)drow * TT + t0 + tc * 8, &Vs[b][seg * 8]);
        }
    };

    stage(0, 0);

    const float C1 = 0.18033688f;    // 0.125 * log2(e)
    const float C2 = -11.5415603f;   // -8 * log2(e)

    for (int it = 0; it < niters; ++it) {
        __syncthreads();               // buf it&1 staged; prior buf free
        const bf16* Kb = &Ks[it & 1][0];
        const bf16* Vb = &Vs[it & 1][0];
        if (it + 1 < niters) stage(it + 1, (it + 1) & 1);

        const int t0 = it * 128;
        // wave-uniform: skip if this wave's 64 keys are all masked for all its q
        if (t0 + kbase > qw + 31 + OFFS) continue;
        const bool full = (t0 + kbase + 63 <= qw + OFFS);  // no masking needed

        // ---- S^T = K·Q^T : 4 key-subtiles of 16 x 2 q-subtiles ----
        // C layout: row = key kbase+kt*16+quad*4+r, col = q = qs*16+l16
        f32x4 s[4][2];
#pragma unroll
        for (int kt = 0; kt < 4; ++kt) {
            int row = kbase + kt * 16 + l16;
            int swz = row & 7;
            bf16x8 ka = *(const bf16x8*)(Kb + (row * 8 + (quad ^ swz)) * 8);
            bf16x8 kb = *(const bf16x8*)(Kb + (row * 8 + ((4 + quad) ^ swz)) * 8);
#pragma unroll
            for (int qs = 0; qs < 2; ++qs) {
                f32x4 z = {0.f, 0.f, 0.f, 0.f};
                z = mfma16(ka, qf[qs][0], z);
                z = mfma16(kb, qf[qs][1], z);
                s[kt][qs] = z;
            }
        }

        // ---- fixed-max softmax, in-register ----
        f32x4 p[4][2];
        if (full) {
#pragma unroll
            for (int kt = 0; kt < 4; ++kt)
#pragma unroll
                for (int qs = 0; qs < 2; ++qs)
#pragma unroll
                    for (int r = 0; r < 4; ++r)
                        p[kt][qs][r] = __builtin_amdgcn_exp2f(fmaf(s[kt][qs][r], C1, C2));
        } else {
#pragma unroll
            for (int qs = 0; qs < 2; ++qs) {
                const int qlim = qw + qs * 16 + l16 + OFFS - t0;  // local key bound
#pragma unroll
                for (int kt = 0; kt < 4; ++kt)
#pragma unroll
                    for (int r = 0; r < 4; ++r) {
                        int tl = kbase + kt * 16 + quad * 4 + r;
                        float e = __builtin_amdgcn_exp2f(fmaf(s[kt][qs][r], C1, C2));
                        p[kt][qs][r] = (tl <= qlim) ? e : 0.f;
                    }
            }
        }
#pragma unroll
        for (int qs = 0; qs < 2; ++qs)
#pragma unroll
            for (int kt = 0; kt < 4; ++kt)
                lsum[qs] += (p[kt][qs][0] + p[kt][qs][1]) + (p[kt][qs][2] + p[kt][qs][3]);

        // ---- P^T as B-frags (2 key-frags of 32); permuted k-order:
        //      frag kf, slot j<4  -> key kbase+kf*32+quad*4+j
        //      frag kf, slot j>=4 -> key kbase+kf*32+16+quad*4+(j-4)
        bf16x8 pf[2][2];
#pragma unroll
        for (int kf = 0; kf < 2; ++kf)
#pragma unroll
            for (int qs = 0; qs < 2; ++qs)
#pragma unroll
                for (int j = 0; j < 4; ++j) {
                    pf[kf][qs][j]     = (bf16)p[kf * 2][qs][j];
                    pf[kf][qs][4 + j] = (bf16)p[kf * 2 + 1][qs][j];
                }

        // ---- O^T += V^T·P^T with SAME k-permutation on the A-operand:
        //      slot j<4  -> chunk kh*8 + kf*4 + q1,     offset h4
        //      slot j>=4 -> chunk kh*8 + kf*4 + 2 + q1, offset h4
        const int q1 = quad >> 1;
        const int h4 = (quad & 1) * 4;   // bf16 units within 16B chunk
#pragma unroll
        for (int dt = 0; dt < 4; ++dt) {
            int row = dt * 16 + l16;
            int swz = row & 15;
#pragma unroll
            for (int kf = 0; kf < 2; ++kf) {
                int c0 = kh * 8 + kf * 4 + q1;
                bf16x4 v0 = *(const bf16x4*)(Vb + (row * 16 + (c0 ^ swz)) * 8 + h4);
                bf16x4 v1 = *(const bf16x4*)(Vb + (row * 16 + ((c0 + 2) ^ swz)) * 8 + h4);
                bf16x8 vf;
#pragma unroll
                for (int j = 0; j < 4; ++j) {
                    vf[j] = v0[j]; vf[4 + j] = v1[j];
                }
#pragma unroll
                for (int qs = 0; qs < 2; ++qs)
                    o[dt][qs] = mfma16(vf, pf[kf][qs], o[dt][qs]);
            }
        }
    }

    // ---- reduce lsum across quads (value for q = qs*16+l16) ----
#pragma unroll
    for (int qs = 0; qs < 2; ++qs) {
        lsum[qs] += __shfl_xor(lsum[qs], 16, 64);
        lsum[qs] += __shfl_xor(lsum[qs], 32, 64);
    }

    // ---- cross-wave (key-half) combine via LDS scratch ----
    __syncthreads();                       // all tile reads done; reuse Ks/Vs
    float* So = (float*)&Ks[0][0];         // 4096 floats: [32 elems][128 lanes]
    float* Sl = (float*)&Vs[0][0];         // 256 floats
    if (kh == 1) {
#pragma unroll
        for (int dt = 0; dt < 4; ++dt)
#pragma unroll
            for (int qs = 0; qs < 2; ++qs)
#pragma unroll
                for (int r = 0; r < 4; ++r)
                    So[(dt * 8 + qs * 4 + r) * 128 + qh * 64 + lane] = o[dt][qs][r];
#pragma unroll
        for (int qs = 0; qs < 2; ++qs)
            Sl[qs * 128 + qh * 64 + lane] = lsum[qs];
    }
    __syncthreads();
    if (kh == 1) return;

#pragma unroll
    for (int dt = 0; dt < 4; ++dt)
#pragma unroll
        for (int qs = 0; qs < 2; ++qs)
#pragma unroll
            for (int r = 0; r < 4; ++r)
                o[dt][qs][r] += So[(dt * 8 + qs * 4 + r) * 128 + qh * 64 + lane];
    float rl[2];
#pragma unroll
    for (int qs = 0; qs < 2; ++qs)
        rl[qs] = 1.f / (lsum[qs] + Sl[qs * 128 + qh * 64 + lane]);

    // o C layout: row = d_local = quad*4+r, col = q = qs*16+l16
    const int b = bh >> 4, h = bh & 15;
#pragma unroll
    for (int qs = 0; qs < 2; ++qs) {
        const int q = qw + qs * 16 + l16;
        bf16* op = Ob + (((size_t)(b * SS + q) * HH) + h) * HD;
#pragma unroll
        for (int dt = 0; dt < 4; ++dt) {
            bf16x4 w;
#pragma unroll
            for (int r = 0; r < 4; ++r) w[r] = (bf16)(o[dt][qs][r] * rl[qs]);
            *(bf16x4*)(op + dt * 16 + quad * 4) = w;
        }
    }
}

extern "C" void kernel_launch(void* const* d_in, const int* in_sizes, int n_in,
                              void* d_out, int out_size, void* d_ws, size_t ws_size,
                              hipStream_t stream) {
    const float* x   = (const float*)d_in[0];
    const float* ck  = (const float*)d_in[1];
    const float* cv  = (const float*)d_in[2];
    const float* Wq  = (const float*)d_in[3];
    const float* bq  = (const float*)d_in[4];
    const float* Wk  = (const float*)d_in[5];
    const float* bk  = (const float*)d_in[6];
    const float* Wv  = (const float*)d_in[7];
    const float* bv  = (const float*)d_in[8];
    const float* Wo  = (const float*)d_in[9];
    const float* bo  = (const float*)d_in[10];
    float* out = (float*)d_out;

    char* ws = (char*)d_ws;
    bf16* xb  = (bf16*)(ws);                   // [2048,1024]        4 MB
    bf16* wqb = (bf16*)(ws + ( 4u << 20));     // Wqkv [3072,1024] contiguous:
    bf16* wkb = (bf16*)(ws + ( 6u << 20));     //   wq 4-6, wk 6-8, wv 8-10 MB
    bf16* wvb = (bf16*)(ws + ( 8u << 20));
    bf16* wob = (bf16*)(ws + (10u << 20));
    bf16* Qb  = (bf16*)(ws + (12u << 20));     // [B,H,S,HD]         4 MB
    bf16* Kf  = (bf16*)(ws + (16u << 20));     // [B,H,TT,HD]        8 MB
    bf16* Vt  = (bf16*)(ws + (24u << 20));     // [B,H,HD,TT]        8 MB
    bf16* Ob  = (bf16*)(ws + (32u << 20));     // [B,S,H,HD]         4 MB

    // all conversions in one launch (8 elems/lane)
    cvt_all<<<4608, 256, 0, stream>>>(x, xb, Wq, Wk, Wv, Wo, wqb, wkb, wvb, wob,
                                      ck, Kf, cv, Vt);

    // QKV projections: one fused GEMM over N=3072 (768 blocks = 3/CU exactly)
    gemm_nt<<<dim3(24, 32), 256, 0, stream>>>(xb, wqb, bq, bk, bv, Qb, Kf, Vt);
    // attention (heavy-first ordering)
    attn<<<512, 256, 0, stream>>>(Qb, Kf, Vt, Ob);
    // output projection (512 blocks = 2/CU) -> fp32 d_out
    gemm_oproj<<<dim3(8, 64), 256, 0, stream>>>(Ob, wob, bo, out);
}

// Round 9
// 153.827 us; speedup vs baseline: 1.0565x; 1.0267x over previous
//
#include <hip/hip_runtime.h>
#include <hip/hip_bf16.h>
#include <stdint.h>

typedef __bf16 bf16;
typedef __bf16 bf16x4 __attribute__((ext_vector_type(4)));
typedef __bf16 bf16x8 __attribute__((ext_vector_type(8)));
typedef float  f32x4  __attribute__((ext_vector_type(4)));

#define DEV __device__ __forceinline__

// ---- constants for this problem ----
#define BB 2
#define HH 16
#define SS 1024
#define DD 1024
#define HD 64
#define LC 1024
#define TT 2048   // LC + SS
#define OFFS 1024 // TT - SS (causal offset)

DEV f32x4 mfma16(bf16x8 a, bf16x8 b, f32x4 c) {
    return __builtin_amdgcn_mfma_f32_16x16x32_bf16(a, b, c, 0, 0, 0);
}

// async global->LDS, 16B per lane. LDS dest must be wave-uniform base + lane*16.
DEV void async_load16(const bf16* g, bf16* lds) {
    auto gp = reinterpret_cast<const __attribute__((address_space(1))) void*>(
        reinterpret_cast<uintptr_t>(g));
    auto lp = reinterpret_cast<__attribute__((address_space(3))) void*>(
        reinterpret_cast<uintptr_t>(lds));
    __builtin_amdgcn_global_load_lds(gp, lp, 16, 0, 0);
}

DEV bf16x8 cvt8(float4 a, float4 b) {
    bf16x8 o;
    o[0] = (bf16)a.x; o[1] = (bf16)a.y; o[2] = (bf16)a.z; o[3] = (bf16)a.w;
    o[4] = (bf16)b.x; o[5] = (bf16)b.y; o[6] = (bf16)b.z; o[7] = (bf16)b.w;
    return o;
}

// ---------------------------------------------------------------------------
// cvt for x + weights only (cache cvt moved into the QKV launch for backfill):
//   blocks [0,1024)     : x fp32 -> xb bf16 (8 elems/lane)
//   blocks [1024,3072)  : Wq/Wk/Wv/Wo fp32 -> bf16 (512 blocks each)
// ---------------------------------------------------------------------------
__global__ __launch_bounds__(256) void cvt_xw(
    const float* __restrict__ x,  bf16* __restrict__ xb,
    const float* __restrict__ w0, const float* __restrict__ w1,
    const float* __restrict__ w2, const float* __restrict__ w3,
    bf16* __restrict__ d0, bf16* __restrict__ d1,
    bf16* __restrict__ d2, bf16* __restrict__ d3) {
    const int bid = blockIdx.x;
    const int tid = threadIdx.x;
    const float* s;
    bf16* d;
    int i;   // float4 index (2 per lane)
    if (bid < 1024) {
        s = x; d = xb; i = bid * 512 + tid * 2;
    } else {
        int which = (bid - 1024) >> 9;
        s = which == 0 ? w0 : which == 1 ? w1 : which == 2 ? w2 : w3;
        d = which == 0 ? d0 : which == 1 ? d1 : which == 2 ? d2 : d3;
        i = ((bid - 1024) & 511) * 512 + tid * 2;
    }
    float4 a = ((const float4*)s)[i];
    float4 b = ((const float4*)s)[i + 1];
    ((bf16x8*)d)[i >> 1] = cvt8(a, b);
}

// ---------------------------------------------------------------------------
// QKV NT GEMM + cache conversion backfill, one launch (2304 blocks):
//   bid [0,768)      : GEMM Y = A·Wqkv^T + bias.  BM=64, BN=128, BK=64.
//                      m fastest (bid&31), n slowest (bid>>5): consecutive 32
//                      blocks share one 256 KB W panel -> W stays hot in each
//                      XCD L2; A (4 MB) ~L2-resident. (Old layout thrashed the
//                      6 MB Wqkv working set through 4 MB L2.)
//   bid [768,1792)   : cache_k fp32 -> Kf rows [0,LC)      (backfills GEMM tail)
//   bid [1792,2304)  : cache_v fp32 -> Vt cols [0,LC) transposed
// Shared 48 KB LDS alias (gemm double-buffers / cvt_v transpose tile).
// ---------------------------------------------------------------------------
__global__ __launch_bounds__(256) void gemm_qkv_cvt(
    const bf16* __restrict__ A, const bf16* __restrict__ W,
    const float* __restrict__ bq, const float* __restrict__ bk,
    const float* __restrict__ bv,
    bf16* __restrict__ Qb, bf16* __restrict__ Kf, bf16* __restrict__ Vt,
    const float* __restrict__ ck, const float* __restrict__ cv) {
    __shared__ __align__(16) char smem[49152];
    const int bid = blockIdx.x;
    const int tid = threadIdx.x;

    if (bid >= 768) {
        if (bid < 1792) {                       // cache_k streaming cvt
            int ii = (bid - 768) * 512 + tid * 2;      // float4 index
            int bh  = ii >> 14;                        // 16384 f4 per bh
            int rem = ii & 16383;
            float4 a = ((const float4*)ck)[ii];
            float4 b = ((const float4*)ck)[ii + 1];
            ((bf16x8*)(Kf + (size_t)bh * TT * HD))[rem >> 1] = cvt8(a, b);
        } else {                                // cache_v 64x64 transpose
            float (*tile)[65] = (float(*)[65])smem;
            int rem = bid - 1792;
            int bh = rem >> 4;
            int t0 = (rem & 15) * 64;
            int c4 = (tid & 15) * 4;
            int rr = tid >> 4;
            const float* src = cv + ((size_t)bh * LC + t0) * HD;
#pragma unroll
            for (int p = 0; p < 4; ++p) {
                int t = rr + p * 16;
                float4 v = *(const float4*)(src + (size_t)t * HD + c4);
                tile[c4 + 0][t] = v.x; tile[c4 + 1][t] = v.y;
                tile[c4 + 2][t] = v.z; tile[c4 + 3][t] = v.w;
            }
            __syncthreads();
            bf16* dst = Vt + (size_t)bh * HD * TT + t0;
#pragma unroll
            for (int p = 0; p < 4; ++p) {
                int d = rr + p * 16;
                int tc = (tid & 15) * 4;
                bf16x4 o;
                o[0] = (bf16)tile[d][tc + 0]; o[1] = (bf16)tile[d][tc + 1];
                o[2] = (bf16)tile[d][tc + 2]; o[3] = (bf16)tile[d][tc + 3];
                *(bf16x4*)(dst + (size_t)d * TT + tc) = o;
            }
        }
        return;
    }

    // ---- GEMM path ----
    bf16* As = (bf16*)smem;               // [2][64*64]   16 KB
    bf16* Bs = (bf16*)(smem + 16384);     // [2][128*64]  32 KB
    const int wv   = tid >> 6;
    const int lane = tid & 63;
    const int l16  = lane & 15;
    const int quad = lane >> 4;
    const int m0 = (bid & 31) * 64;       // m fastest
    const int n0 = (bid >> 5) * 128;      // n slowest -> W panel shared
    const int mode = n0 >> 10;
    const float* bias = (mode == 0) ? bq : (mode == 1) ? bk : bv;

    f32x4 acc[4][2];
#pragma unroll
    for (int i = 0; i < 4; ++i)
#pragma unroll
        for (int j = 0; j < 2; ++j) {
            f32x4 z = {0.f, 0.f, 0.f, 0.f};
            acc[i][j] = z;
        }

    auto stage = [&](int k0, int b) {
#pragma unroll
        for (int k = 0; k < 2; ++k) {
            int seg = k * 256 + tid;
            int row = seg >> 3;
            int c   = (seg & 7) ^ (row & 7);
            async_load16(A + (size_t)(m0 + row) * 1024 + k0 + c * 8,
                         As + b * 4096 + seg * 8);
        }
#pragma unroll
        for (int k = 0; k < 4; ++k) {
            int seg = k * 256 + tid;
            int row = seg >> 3;
            int c   = (seg & 7) ^ (row & 7);
            async_load16(W + (size_t)(n0 + row) * 1024 + k0 + c * 8,
                         Bs + b * 8192 + seg * 8);
        }
    };

    stage(0, 0);

    for (int it = 0; it < 16; ++it) {
        __syncthreads();
        const bf16* Ab = As + (it & 1) * 4096;
        const bf16* Bb = Bs + (it & 1) * 8192;
        if (it + 1 < 16) stage((it + 1) * 64, (it + 1) & 1);

#pragma unroll
        for (int kk = 0; kk < 2; ++kk) {
            bf16x8 af[4], bfr[2];
#pragma unroll
            for (int i = 0; i < 4; ++i) {
                int row = i * 16 + l16;
                int slot = (kk * 4 + quad) ^ (row & 7);
                af[i] = *(const bf16x8*)(Ab + (row * 8 + slot) * 8);
            }
#pragma unroll
            for (int j = 0; j < 2; ++j) {
                int row = wv * 32 + j * 16 + l16;
                int slot = (kk * 4 + quad) ^ (row & 7);
                bfr[j] = *(const bf16x8*)(Bb + (row * 8 + slot) * 8);
            }
#pragma unroll
            for (int i = 0; i < 4; ++i)
#pragma unroll
                for (int j = 0; j < 2; ++j)
                    acc[i][j] = mfma16(af[i], bfr[j], acc[i][j]);
        }
    }

    // epilogue: C layout col = l16 (n), row = quad*4 + r (m)
#pragma unroll
    for (int i = 0; i < 4; ++i) {
#pragma unroll
        for (int j = 0; j < 2; ++j) {
            int n = n0 + wv * 32 + j * 16 + l16;
            float bval = bias[n & 1023];
#pragma unroll
            for (int r = 0; r < 4; ++r) {
                int m = m0 + i * 16 + quad * 4 + r;
                float v = acc[i][j][r] + bval;
                int b = m >> 10, s = m & 1023;
                int h = (n & 1023) >> 6, d = n & 63;
                int bh = b * HH + h;
                if (mode == 0)
                    Qb[((size_t)bh * SS + s) * HD + d] = (bf16)v;
                else if (mode == 1)
                    Kf[((size_t)bh * TT + LC + s) * HD + d] = (bf16)v;
                else
                    Vt[((size_t)bh * HD + d) * TT + LC + s] = (bf16)v;
            }
        }
    }
}

// ---------------------------------------------------------------------------
// Output projection GEMM: Out[m,n] = sum_k Ob[m,k] * Wo[n,k] + bo[n], fp32 out.
//   BM=32, BN=128 -> grid (8,64) = 512 blocks = 2/CU. LDS 40 KB.
// ---------------------------------------------------------------------------
__global__ __launch_bounds__(256) void gemm_oproj(
    const bf16* __restrict__ A, const bf16* __restrict__ W,
    const float* __restrict__ bo, float* __restrict__ Out) {
    const int tid  = threadIdx.x;
    const int wv   = tid >> 6;
    const int lane = tid & 63;
    const int l16  = lane & 15;
    const int quad = lane >> 4;
    const int m0 = blockIdx.y * 32;
    const int n0 = blockIdx.x * 128;

    __shared__ __align__(16) bf16 As[2][32 * 64];
    __shared__ __align__(16) bf16 Bs[2][128 * 64];

    f32x4 acc[2][2];
#pragma unroll
    for (int i = 0; i < 2; ++i)
#pragma unroll
        for (int j = 0; j < 2; ++j) {
            f32x4 z = {0.f, 0.f, 0.f, 0.f};
            acc[i][j] = z;
        }

    auto stage = [&](int k0, int b) {
        {
            int seg = tid;                 // A: 256 chunks (32 rows x 8)
            int row = seg >> 3;
            int c   = (seg & 7) ^ (row & 7);
            async_load16(A + (size_t)(m0 + row) * 1024 + k0 + c * 8, &As[b][seg * 8]);
        }
#pragma unroll
        for (int k = 0; k < 4; ++k) {      // B: 1024 chunks (128 rows x 8)
            int seg = k * 256 + tid;
            int row = seg >> 3;
            int c   = (seg & 7) ^ (row & 7);
            async_load16(W + (size_t)(n0 + row) * 1024 + k0 + c * 8, &Bs[b][seg * 8]);
        }
    };

    stage(0, 0);

    for (int it = 0; it < 16; ++it) {
        __syncthreads();
        const bf16* Ab = &As[it & 1][0];
        const bf16* Bb = &Bs[it & 1][0];
        if (it + 1 < 16) stage((it + 1) * 64, (it + 1) & 1);

#pragma unroll
        for (int kk = 0; kk < 2; ++kk) {
            bf16x8 af[2], bfr[2];
#pragma unroll
            for (int i = 0; i < 2; ++i) {
                int row = i * 16 + l16;
                int slot = (kk * 4 + quad) ^ (row & 7);
                af[i] = *(const bf16x8*)(Ab + (row * 8 + slot) * 8);
            }
#pragma unroll
            for (int j = 0; j < 2; ++j) {
                int row = wv * 32 + j * 16 + l16;
                int slot = (kk * 4 + quad) ^ (row & 7);
                bfr[j] = *(const bf16x8*)(Bb + (row * 8 + slot) * 8);
            }
#pragma unroll
            for (int i = 0; i < 2; ++i)
#pragma unroll
                for (int j = 0; j < 2; ++j)
                    acc[i][j] = mfma16(af[i], bfr[j], acc[i][j]);
        }
    }

#pragma unroll
    for (int i = 0; i < 2; ++i) {
#pragma unroll
        for (int j = 0; j < 2; ++j) {
            int n = n0 + wv * 32 + j * 16 + l16;
            float bval = bo[n];
#pragma unroll
            for (int r = 0; r < 4; ++r) {
                int m = m0 + i * 16 + quad * 4 + r;
                Out[(size_t)m * 1024 + n] = acc[i][j][r] + bval;
            }
        }
    }
}

// ---------------------------------------------------------------------------
// Flash attention v6 (R6-verified) + heavy-first dispatch ordering.
// ---------------------------------------------------------------------------
__global__ __launch_bounds__(256) void attn(const bf16* __restrict__ Qb,
                                            const bf16* __restrict__ Kf,
                                            const bf16* __restrict__ Vt,
                                            bf16* __restrict__ Ob) {
    const int i = blockIdx.x;
    const int bh = i & 31;
    const int qblk = 15 - (i >> 5);
    const int tid  = threadIdx.x;
    const int wv   = tid >> 6;
    const int qh   = wv & 1;
    const int kh   = wv >> 1;
    const int lane = tid & 63;
    const int l16  = lane & 15;
    const int quad = lane >> 4;
    const int qb   = qblk * 64;            // block q base
    const int qw   = qb + qh * 32;         // wave q base (32 rows)
    const int kbase = kh * 64;             // wave key offset within 128-tile

    const bf16* Qp = Qb + ((size_t)bh * SS + qw) * HD;
    const bf16* Kp = Kf + (size_t)bh * TT * HD;
    const bf16* Vp = Vt + (size_t)bh * HD * TT;

    __shared__ __align__(16) bf16 Ks[2][128 * 64];
    __shared__ __align__(16) bf16 Vs[2][64 * 128];

    // Q as B-operand: qf[qs][dc] = B[k=d=dc*32+quad*8+j][n=q=qs*16+l16]
    bf16x8 qf[2][2];
#pragma unroll
    for (int qs = 0; qs < 2; ++qs)
#pragma unroll
        for (int dc = 0; dc < 2; ++dc)
            qf[qs][dc] = *(const bf16x8*)(Qp + (qs * 16 + l16) * HD + dc * 32 + quad * 8);

    float lsum[2] = {0.f, 0.f};
    f32x4 o[4][2];
#pragma unroll
    for (int dt = 0; dt < 4; ++dt)
#pragma unroll
        for (int qs = 0; qs < 2; ++qs) {
            f32x4 z = {0.f, 0.f, 0.f, 0.f};
            o[dt][qs] = z;
        }

    const int niters = qblk / 2 + 9;   // ceil((qb + 64 + OFFS) / 128)

    // stage 128-key tile into buffer b; XOR chunk swizzle on global address
    auto stage = [&](int tile, int b) {
        const int t0 = tile * 128;
#pragma unroll
        for (int j = 0; j < 4; ++j) {
            int seg = j * 256 + tid;               // 0..1023
            int krow = seg >> 3;                   // key 0..127
            int kc   = (seg & 7) ^ (krow & 7);
            async_load16(Kp + (size_t)(t0 + krow) * HD + kc * 8, &Ks[b][seg * 8]);
            int drow = seg >> 4;                   // d 0..63
            int tc   = (seg & 15) ^ (drow & 15);
            async_load16(Vp + (size_t)drow * TT + t0 + tc * 8, &Vs[b][seg * 8]);
        }
    };

    stage(0, 0);

    const float C1 = 0.18033688f;    // 0.125 * log2(e)
    const float C2 = -11.5415603f;   // -8 * log2(e)

    for (int it = 0; it < niters; ++it) {
        __syncthreads();               // buf it&1 staged; prior buf free
        const bf16* Kb = &Ks[it & 1][0];
        const bf16* Vb = &Vs[it & 1][0];
        if (it + 1 < niters) stage(it + 1, (it + 1) & 1);

        const int t0 = it * 128;
        // wave-uniform: skip if this wave's 64 keys are all masked for all its q
        if (t0 + kbase > qw + 31 + OFFS) continue;
        const bool full = (t0 + kbase + 63 <= qw + OFFS);  // no masking needed

        // ---- S^T = K·Q^T : 4 key-subtiles of 16 x 2 q-subtiles ----
        // C layout: row = key kbase+kt*16+quad*4+r, col = q = qs*16+l16
        f32x4 s[4][2];
#pragma unroll
        for (int kt = 0; kt < 4; ++kt) {
            int row = kbase + kt * 16 + l16;
            int swz = row & 7;
            bf16x8 ka = *(const bf16x8*)(Kb + (row * 8 + (quad ^ swz)) * 8);
            bf16x8 kb = *(const bf16x8*)(Kb + (row * 8 + ((4 + quad) ^ swz)) * 8);
#pragma unroll
            for (int qs = 0; qs < 2; ++qs) {
                f32x4 z = {0.f, 0.f, 0.f, 0.f};
                z = mfma16(ka, qf[qs][0], z);
                z = mfma16(kb, qf[qs][1], z);
                s[kt][qs] = z;
            }
        }

        // ---- fixed-max softmax, in-register ----
        f32x4 p[4][2];
        if (full) {
#pragma unroll
            for (int kt = 0; kt < 4; ++kt)
#pragma unroll
                for (int qs = 0; qs < 2; ++qs)
#pragma unroll
                    for (int r = 0; r < 4; ++r)
                        p[kt][qs][r] = __builtin_amdgcn_exp2f(fmaf(s[kt][qs][r], C1, C2));
        } else {
#pragma unroll
            for (int qs = 0; qs < 2; ++qs) {
                const int qlim = qw + qs * 16 + l16 + OFFS - t0;  // local key bound
#pragma unroll
                for (int kt = 0; kt < 4; ++kt)
#pragma unroll
                    for (int r = 0; r < 4; ++r) {
                        int tl = kbase + kt * 16 + quad * 4 + r;
                        float e = __builtin_amdgcn_exp2f(fmaf(s[kt][qs][r], C1, C2));
                        p[kt][qs][r] = (tl <= qlim) ? e : 0.f;
                    }
            }
        }
#pragma unroll
        for (int qs = 0; qs < 2; ++qs)
#pragma unroll
            for (int kt = 0; kt < 4; ++kt)
                lsum[qs] += (p[kt][qs][0] + p[kt][qs][1]) + (p[kt][qs][2] + p[kt][qs][3]);

        // ---- P^T as B-frags (2 key-frags of 32); permuted k-order:
        //      frag kf, slot j<4  -> key kbase+kf*32+quad*4+j
        //      frag kf, slot j>=4 -> key kbase+kf*32+16+quad*4+(j-4)
        bf16x8 pf[2][2];
#pragma unroll
        for (int kf = 0; kf < 2; ++kf)
#pragma unroll
            for (int qs = 0; qs < 2; ++qs)
#pragma unroll
                for (int j = 0; j < 4; ++j) {
                    pf[kf][qs][j]     = (bf16)p[kf * 2][qs][j];
                    pf[kf][qs][4 + j] = (bf16)p[kf * 2 + 1][qs][j];
                }

        // ---- O^T += V^T·P^T with SAME k-permutation on the A-operand:
        //      slot j<4  -> chunk kh*8 + kf*4 + q1,     offset h4
        //      slot j>=4 -> chunk kh*8 + kf*4 + 2 + q1, offset h4
        const int q1 = quad >> 1;
        const int h4 = (quad & 1) * 4;   // bf16 units within 16B chunk
#pragma unroll
        for (int dt = 0; dt < 4; ++dt) {
            int row = dt * 16 + l16;
            int swz = row & 15;
#pragma unroll
            for (int kf = 0; kf < 2; ++kf) {
                int c0 = kh * 8 + kf * 4 + q1;
                bf16x4 v0 = *(const bf16x4*)(Vb + (row * 16 + (c0 ^ swz)) * 8 + h4);
                bf16x4 v1 = *(const bf16x4*)(Vb + (row * 16 + ((c0 + 2) ^ swz)) * 8 + h4);
                bf16x8 vf;
#pragma unroll
                for (int j = 0; j < 4; ++j) {
                    vf[j] = v0[j]; vf[4 + j] = v1[j];
                }
#pragma unroll
                for (int qs = 0; qs < 2; ++qs)
                    o[dt][qs] = mfma16(vf, pf[kf][qs], o[dt][qs]);
            }
        }
    }

    // ---- reduce lsum across quads (value for q = qs*16+l16) ----
#pragma unroll
    for (int qs = 0; qs < 2; ++qs) {
        lsum[qs] += __shfl_xor(lsum[qs], 16, 64);
        lsum[qs] += __shfl_xor(lsum[qs], 32, 64);
    }

    // ---- cross-wave (key-half) combine via LDS scratch ----
    __syncthreads();                       // all tile reads done; reuse Ks/Vs
    float* So = (float*)&Ks[0][0];         // 4096 floats: [32 elems][128 lanes]
    float* Sl = (float*)&Vs[0][0];         // 256 floats
    if (kh == 1) {
#pragma unroll
        for (int dt = 0; dt < 4; ++dt)
#pragma unroll
            for (int qs = 0; qs < 2; ++qs)
#pragma unroll
                for (int r = 0; r < 4; ++r)
                    So[(dt * 8 + qs * 4 + r) * 128 + qh * 64 + lane] = o[dt][qs][r];
#pragma unroll
        for (int qs = 0; qs < 2; ++qs)
            Sl[qs * 128 + qh * 64 + lane] = lsum[qs];
    }
    __syncthreads();
    if (kh == 1) return;

#pragma unroll
    for (int dt = 0; dt < 4; ++dt)
#pragma unroll
        for (int qs = 0; qs < 2; ++qs)
#pragma unroll
            for (int r = 0; r < 4; ++r)
                o[dt][qs][r] += So[(dt * 8 + qs * 4 + r) * 128 + qh * 64 + lane];
    float rl[2];
#pragma unroll
    for (int qs = 0; qs < 2; ++qs)
        rl[qs] = 1.f / (lsum[qs] + Sl[qs * 128 + qh * 64 + lane]);

    // o C layout: row = d_local = quad*4+r, col = q = qs*16+l16
    const int b = bh >> 4, h = bh & 15;
#pragma unroll
    for (int qs = 0; qs < 2; ++qs) {
        const int q = qw + qs * 16 + l16;
        bf16* op = Ob + (((size_t)(b * SS + q) * HH) + h) * HD;
#pragma unroll
        for (int dt = 0; dt < 4; ++dt) {
            bf16x4 w;
#pragma unroll
            for (int r = 0; r < 4; ++r) w[r] = (bf16)(o[dt][qs][r] * rl[qs]);
            *(bf16x4*)(op + dt * 16 + quad * 4) = w;
        }
    }
}

extern "C" void kernel_launch(void* const* d_in, const int* in_sizes, int n_in,
                              void* d_out, int out_size, void* d_ws, size_t ws_size,
                              hipStream_t stream) {
    const float* x   = (const float*)d_in[0];
    const float* ck  = (const float*)d_in[1];
    const float* cv  = (const float*)d_in[2];
    const float* Wq  = (const float*)d_in[3];
    const float* bq  = (const float*)d_in[4];
    const float* Wk  = (const float*)d_in[5];
    const float* bk  = (const float*)d_in[6];
    const float* Wv  = (const float*)d_in[7];
    const float* bv  = (const float*)d_in[8];
    const float* Wo  = (const float*)d_in[9];
    const float* bo  = (const float*)d_in[10];
    float* out = (float*)d_out;

    char* ws = (char*)d_ws;
    bf16* xb  = (bf16*)(ws);                   // [2048,1024]        4 MB
    bf16* wqb = (bf16*)(ws + ( 4u << 20));     // Wqkv [3072,1024] contiguous:
    bf16* wkb = (bf16*)(ws + ( 6u << 20));     //   wq 4-6, wk 6-8, wv 8-10 MB
    bf16* wvb = (bf16*)(ws + ( 8u << 20));
    bf16* wob = (bf16*)(ws + (10u << 20));
    bf16* Qb  = (bf16*)(ws + (12u << 20));     // [B,H,S,HD]         4 MB
    bf16* Kf  = (bf16*)(ws + (16u << 20));     // [B,H,TT,HD]        8 MB
    bf16* Vt  = (bf16*)(ws + (24u << 20));     // [B,H,HD,TT]        8 MB
    bf16* Ob  = (bf16*)(ws + (32u << 20));     // [B,S,H,HD]         4 MB

    // x + weight conversion (cache conversion rides with the QKV launch)
    cvt_xw<<<3072, 256, 0, stream>>>(x, xb, Wq, Wk, Wv, Wo, wqb, wkb, wvb, wob);

    // QKV GEMM (768 blocks, W-panel-major) + cache cvt backfill (1536 blocks)
    gemm_qkv_cvt<<<2304, 256, 0, stream>>>(xb, wqb, bq, bk, bv, Qb, Kf, Vt, ck, cv);

    // attention (heavy-first ordering)
    attn<<<512, 256, 0, stream>>>(Qb, Kf, Vt, Ob);

    // output projection (512 blocks = 2/CU) -> fp32 d_out
    gemm_oproj<<<dim3(8, 64), 256, 0, stream>>>(Ob, wob, bo, out);
}